// Round 4
// baseline (327.531 us; speedup 1.0000x reference)
//
#include <hip/hip_runtime.h>

// Problem constants (TextEncoder_55671366091616)
#define BB 32
#define SS 2048
#define DD 1024
#define EE 64
#define KK 8
#define TT 128            // N_TAGS
#define MM (BB * EE)      // 2048 output rows

#define MT 8              // entities per block
#define KC 128            // K columns per W chunk
#define ASTR 1032         // As row stride (bf16): 2064 B = 516 dw == 4 mod 32
#define WSTR 136          // Ws row stride (bf16): 272 B = 68 dw == 4 mod 32

typedef __attribute__((ext_vector_type(8))) short short8;   // bf16x8 frag
typedef __attribute__((ext_vector_type(4))) float f32x4;    // MFMA accumulator

__device__ __forceinline__ unsigned short f2bf(float f) {
    union { float f; unsigned int u; } v; v.f = f;
    unsigned int u = v.u + 0x7FFFu + ((v.u >> 16) & 1u);
    return (unsigned short)(u >> 16);
}

// ---------------------------------------------------------------------------
// Single fused kernel: gather + mean-pool + bf16 MFMA FC + bias.
// grid = M/MT = 256 blocks (1/CU), 256 threads (4 waves).
//  Stage A: 32 threads per entity, interleaved float4 mapping (lane c owns
//           float4 indices {j*32+c}) -> consecutive lanes read consecutive
//           16 B. fp32 acc in regs, scale, bf16 -> As[8][ASTR].
//  K loop:  8 chunks of 128 cols. Stage Ws[128][WSTR] bf16 from fp32 fc_w
//           (L2-resident), then 4 ksteps x 2 n-subtiles MFMA per wave.
//           A-frag rows 8..15 read clamped (lm&7); D rows 8..15 discarded.
//  Epilogue: lanes 0..31 hold rows 0..7; add bias, store fp32 to out.
// ---------------------------------------------------------------------------
__global__ __launch_bounds__(256) void te_fused_kernel(
    const float* __restrict__ hs,        // [B,S,D]
    const int*   __restrict__ subw_idx,  // [B,E,K]
    const int*   __restrict__ subw_cnt,  // [B,E]
    const int*   __restrict__ num_ent,   // [B]
    const float* __restrict__ fc_w,      // [T,D]
    const float* __restrict__ fc_b,      // [T]
    float* __restrict__ out)             // [M,T]
{
    __shared__ unsigned short As[MT][ASTR];   // 16.1 KB (8 rows used)
    __shared__ unsigned short Ws[TT][WSTR];   // 34.8 KB

    const int mt   = blockIdx.x;         // 0..255
    const int t    = threadIdx.x;
    const int wid  = t >> 6;
    const int lane = t & 63;

    // ---- Stage A: gather + mean-pool 8 entities x 1024 cols ----
    {
        const int r  = t >> 5;           // entity row 0..7
        const int c  = t & 31;           // lane-in-group
        const int be = mt * MT + r;
        const int b  = be >> 6;
        const int e  = be & 63;
        const int cnt = subw_cnt[be];
        const int ne  = num_ent[b];
        const float scale = (e < ne) ? (1.0f / (float)cnt) : 0.0f;
        const int* idxp = subw_idx + (size_t)be * KK;

        float4 acc4[8];
        #pragma unroll
        for (int j = 0; j < 8; ++j) acc4[j] = make_float4(0.f, 0.f, 0.f, 0.f);

        for (int k = 0; k < cnt; ++k) {
            const int s = idxp[k];
            const float4* row = (const float4*)(hs + ((size_t)b * SS + s) * DD);
            #pragma unroll
            for (int j = 0; j < 8; ++j) {
                float4 v = row[j * 32 + c];
                acc4[j].x += v.x; acc4[j].y += v.y;
                acc4[j].z += v.z; acc4[j].w += v.w;
            }
        }
        #pragma unroll
        for (int j = 0; j < 8; ++j) {
            ushort4 o;
            o.x = f2bf(acc4[j].x * scale); o.y = f2bf(acc4[j].y * scale);
            o.z = f2bf(acc4[j].z * scale); o.w = f2bf(acc4[j].w * scale);
            *(ushort4*)&As[r][(j * 32 + c) * 4] = o;   // 8 B store, 2-way max
        }
    }

    // ---- K-chunk loop: stage W chunk, MFMA ----
    const int nbase = wid * 32;          // wave's 32-tag N range
    const int lm  = lane & 15;
    const int lq  = (lane >> 4) * 8;
    const int lmA = lm & 7;              // clamp A rows (8..15 duplicate 0..7)

    f32x4 acc0 = {0.f,0.f,0.f,0.f}, acc1 = {0.f,0.f,0.f,0.f};

    const int n = t >> 1;                // W staging: tag row 0..127
    const int h = (t & 1) * 64;          // col half within chunk

    for (int kc = 0; kc < DD / KC; ++kc) {
        __syncthreads();                 // Ws reuse / As ready (first iter)
        {
            const float4* wrow = (const float4*)(fc_w + (size_t)n * DD + kc * KC + h);
            #pragma unroll
            for (int j = 0; j < 16; ++j) {
                float4 v = wrow[j];
                ushort4 o;
                o.x = f2bf(v.x); o.y = f2bf(v.y);
                o.z = f2bf(v.z); o.w = f2bf(v.w);
                *(ushort4*)&Ws[n][h + j * 4] = o;
            }
        }
        __syncthreads();

        #pragma unroll
        for (int kstep = 0; kstep < KC / 32; ++kstep) {
            const int ko = kstep * 32 + lq;
            short8 a  = *(const short8*)&As[lmA][kc * KC + ko];
            short8 b0 = *(const short8*)&Ws[nbase +  0 + lm][ko];
            short8 b1 = *(const short8*)&Ws[nbase + 16 + lm][ko];
            acc0 = __builtin_amdgcn_mfma_f32_16x16x32_bf16(a, b0, acc0, 0, 0, 0);
            acc1 = __builtin_amdgcn_mfma_f32_16x16x32_bf16(a, b1, acc1, 0, 0, 0);
        }
    }

    // ---- Epilogue: lanes 0..31 hold D rows 0..7 ----
    if (lane < 32) {
        const int mrow = mt * MT + (lane >> 4) * 4;
        const int c0 = nbase + lm;
        const float b0v = fc_b[c0];
        const float b1v = fc_b[c0 + 16];
        #pragma unroll
        for (int r = 0; r < 4; ++r) {
            float* o = out + (size_t)(mrow + r) * TT + c0;
            o[0]  = acc0[r] + b0v;
            o[16] = acc1[r] + b1v;
        }
    }
}

extern "C" void kernel_launch(void* const* d_in, const int* in_sizes, int n_in,
                              void* d_out, int out_size, void* d_ws, size_t ws_size,
                              hipStream_t stream) {
    const float* hs       = (const float*)d_in[0];
    const int*   subw_idx = (const int*)  d_in[1];
    const int*   subw_cnt = (const int*)  d_in[2];
    const int*   num_ent  = (const int*)  d_in[3];
    const float* fc_w     = (const float*)d_in[4];
    const float* fc_b     = (const float*)d_in[5];
    float*       out      = (float*)d_out;

    te_fused_kernel<<<MM / MT, 256, 0, stream>>>(
        hs, subw_idx, subw_cnt, num_ent, fc_w, fc_b, out);
}

// Round 5
// 319.869 us; speedup vs baseline: 1.0240x; 1.0240x over previous
//
#include <hip/hip_runtime.h>

// Problem constants (TextEncoder_55671366091616)
#define BB 32
#define SS 2048
#define DD 1024
#define EE 64
#define KK 8
#define TT 128            // N_TAGS
#define MM (BB * EE)      // 2048 output rows

#define GMT 16            // GEMM M-tile (rows per block)
#define KC  128           // K columns per Ws chunk
#define ASTR 1032         // As row stride bf16: 2064 B = 516 dw == 4 (mod 32)
#define WSTR 136          // Ws row stride bf16: 272 B = 68 dw == 4 (mod 32)

typedef __attribute__((ext_vector_type(8))) short short8;   // bf16x8 frag
typedef __attribute__((ext_vector_type(4))) float f32x4;    // MFMA accumulator

__device__ __forceinline__ unsigned short f2bf(float f) {
    union { float f; unsigned int u; } v; v.f = f;
    unsigned int u = v.u + 0x7FFFu + ((v.u >> 16) & 1u);
    return (unsigned short)(u >> 16);
}

// ---------------------------------------------------------------------------
// Kernel A: gather + masked mean-pool -> entb bf16 [M,D]; convert W -> bf16.
// grid = 2048 blocks x 256 threads (8 blocks/CU, 32 waves/CU: the gather
// needs this occupancy — round-4's 4-wave/CU fusion was latency-bound).
// ---------------------------------------------------------------------------
__global__ __launch_bounds__(256) void pool_kernel(
    const float* __restrict__ hs,        // [B,S,D]
    const int*   __restrict__ subw_idx,  // [B,E,K]
    const int*   __restrict__ subw_cnt,  // [B,E]
    const int*   __restrict__ num_ent,   // [B]
    const float* __restrict__ fc_w,      // [T,D]
    unsigned short* __restrict__ entb,   // ws: [M,D] bf16
    unsigned short* __restrict__ wb)     // ws: [T,D] bf16
{
    const int be = blockIdx.x;
    const int b  = be >> 6;
    const int e  = be & 63;
    const int t  = threadIdx.x;

    const int cnt = subw_cnt[be];                 // block-uniform
    const int ne  = num_ent[b];
    const float scale = (e < ne) ? (1.0f / (float)cnt) : 0.0f;

    const int* idxp = subw_idx + (size_t)be * KK;

    float4 acc = make_float4(0.f, 0.f, 0.f, 0.f);
    #pragma unroll
    for (int k = 0; k < KK; ++k) {
        if (k < cnt) {                            // block-uniform branch
            const int s = idxp[k];
            const float4* row = (const float4*)(hs + ((size_t)b * SS + s) * DD);
            float4 v = row[t];
            acc.x += v.x; acc.y += v.y; acc.z += v.z; acc.w += v.w;
        }
    }
    ushort4 o;
    o.x = f2bf(acc.x * scale); o.y = f2bf(acc.y * scale);
    o.z = f2bf(acc.z * scale); o.w = f2bf(acc.w * scale);
    *(ushort4*)(entb + (size_t)be * DD + 4 * t) = o;

    // Convert 64 fc_w elems per block: 2048*64 = 131072 = T*D.
    if (t < 64) {
        const int j = be * 64 + t;
        wb[j] = f2bf(fc_w[j]);
    }
}

// ---------------------------------------------------------------------------
// Kernel B: bf16 MFMA GEMM, no split-K, bias fused, writes out directly.
// grid = M/GMT = 128 blocks, 256 threads (4 waves).
// Block: 16 M x 128 N x 1024 K. Wave wid: nbase = wid*32 (2 n-subtiles).
// As staged once (16x1024 bf16, 33 KB); Ws per 128-col chunk (34.8 KB).
// Both LDS strides == 4 dw (mod 32): b128 frag loads are 2-way max (free).
// Full M utilization (16 real rows per MFMA), 64 MFMAs/wave.
// ---------------------------------------------------------------------------
__global__ __launch_bounds__(256) void gemm_kernel(
    const unsigned short* __restrict__ entb, // [M,D] bf16
    const unsigned short* __restrict__ wb,   // [T,D] bf16
    const float* __restrict__ fc_b,          // [T]
    float* __restrict__ out)                 // [M,T]
{
    __shared__ unsigned short As[GMT][ASTR]; // 33.0 KB
    __shared__ unsigned short Ws[TT][WSTR];  // 34.8 KB

    const int mt   = blockIdx.x;         // 0..127
    const int t    = threadIdx.x;
    const int wid  = t >> 6;
    const int lane = t & 63;

    // Stage A: 16 rows x 1024 bf16 = 2048 x 16B; 8 chunks per thread.
    #pragma unroll
    for (int p = 0; p < 8; ++p) {
        const int i   = p * 256 + t;
        const int row = i >> 7;          // 128 x 16B chunks per row
        const int c   = i & 127;
        *(float4*)&As[row][c * 8] =
            *(const float4*)(entb + (size_t)(mt * GMT + row) * DD + c * 8);
    }

    const int nbase = wid * 32;
    const int lm = lane & 15;
    const int lq = (lane >> 4) * 8;

    f32x4 acc0 = {0.f,0.f,0.f,0.f}, acc1 = {0.f,0.f,0.f,0.f};

    for (int kc = 0; kc < DD / KC; ++kc) {
        __syncthreads();                 // Ws reuse (and As-ready at kc=0)
        // Stage Ws chunk: 128 rows x 128 bf16 = 2048 x 16B, pure copy.
        #pragma unroll
        for (int p = 0; p < 8; ++p) {
            const int i   = p * 256 + t;
            const int row = i >> 4;      // 16 x 16B chunks per row
            const int c   = i & 15;
            *(float4*)&Ws[row][c * 8] =
                *(const float4*)(wb + (size_t)row * DD + kc * KC + c * 8);
        }
        __syncthreads();

        #pragma unroll
        for (int kstep = 0; kstep < KC / 32; ++kstep) {
            const int ko = kstep * 32 + lq;
            short8 a  = *(const short8*)&As[lm][kc * KC + ko];
            short8 b0 = *(const short8*)&Ws[nbase +  0 + lm][ko];
            short8 b1 = *(const short8*)&Ws[nbase + 16 + lm][ko];
            acc0 = __builtin_amdgcn_mfma_f32_16x16x32_bf16(a, b0, acc0, 0, 0, 0);
            acc1 = __builtin_amdgcn_mfma_f32_16x16x32_bf16(a, b1, acc1, 0, 0, 0);
        }
    }

    // Epilogue: D[row=(lane>>4)*4+r][col=lane&15]; add bias, store fp32.
    const int mrow = mt * GMT + (lane >> 4) * 4;
    const int c0   = nbase + lm;
    const float b0v = fc_b[c0];
    const float b1v = fc_b[c0 + 16];
    #pragma unroll
    for (int r = 0; r < 4; ++r) {
        float* o = out + (size_t)(mrow + r) * TT + c0;
        o[0]  = acc0[r] + b0v;
        o[16] = acc1[r] + b1v;
    }
}

extern "C" void kernel_launch(void* const* d_in, const int* in_sizes, int n_in,
                              void* d_out, int out_size, void* d_ws, size_t ws_size,
                              hipStream_t stream) {
    const float* hs       = (const float*)d_in[0];
    const int*   subw_idx = (const int*)  d_in[1];
    const int*   subw_cnt = (const int*)  d_in[2];
    const int*   num_ent  = (const int*)  d_in[3];
    const float* fc_w     = (const float*)d_in[4];
    const float* fc_b     = (const float*)d_in[5];
    float*       out      = (float*)d_out;

    unsigned short* entb = (unsigned short*)d_ws;                       // 4 MB
    unsigned short* wb   = (unsigned short*)((char*)d_ws + (size_t)MM * DD * 2);

    pool_kernel<<<MM, 256, 0, stream>>>(hs, subw_idx, subw_cnt, num_ent,
                                        fc_w, entb, wb);
    gemm_kernel<<<MM / GMT, 256, 0, stream>>>(entb, wb, fc_b, out);
}